// Round 4
// baseline (844.771 us; speedup 1.0000x reference)
//
#include <hip/hip_runtime.h>
#include <stdint.h>
#include <math.h>

#define B_ 16
#define T_ 2048
#define D_ 256
#define N_ (B_*T_*D_)   // 8388608

typedef __attribute__((ext_vector_type(8)))  __bf16 bf16x8;
typedef __attribute__((ext_vector_type(4)))  __bf16 bf16x4;
typedef __attribute__((ext_vector_type(2)))  __bf16 bf16x2;
typedef __attribute__((ext_vector_type(4)))  float  f32x4;

// ---------------- JAX threefry2x32 (partitionable layout) ----------------
__device__ __forceinline__ uint32_t rotl32(uint32_t v, int r) {
  return (v << r) | (v >> (32 - r));
}

__device__ __forceinline__ void threefry2x32(uint32_t k0, uint32_t k1,
                                             uint32_t x0, uint32_t x1,
                                             uint32_t& o0, uint32_t& o1) {
  uint32_t ks2 = k0 ^ k1 ^ 0x1BD11BDAu;
#define TF_ROUND(r) { x0 += x1; x1 = rotl32(x1, r); x1 ^= x0; }
  x0 += k0; x1 += k1;
  TF_ROUND(13) TF_ROUND(15) TF_ROUND(26) TF_ROUND(6)
  x0 += k1; x1 += ks2 + 1u;
  TF_ROUND(17) TF_ROUND(29) TF_ROUND(16) TF_ROUND(24)
  x0 += ks2; x1 += k0 + 2u;
  TF_ROUND(13) TF_ROUND(15) TF_ROUND(26) TF_ROUND(6)
  x0 += k0; x1 += k1 + 3u;
  TF_ROUND(17) TF_ROUND(29) TF_ROUND(16) TF_ROUND(24)
  x0 += k1; x1 += ks2 + 4u;
  TF_ROUND(13) TF_ROUND(15) TF_ROUND(26) TF_ROUND(6)
  x0 += ks2; x1 += k0 + 5u;
#undef TF_ROUND
  o0 = x0; o1 = x1;
}

// XLA ErfInv f32 polynomial (Giles)
__device__ __forceinline__ float erfinv_xla(float x) {
  float w = -log1pf(-x * x);
  float p;
  if (w < 5.0f) {
    w -= 2.5f;
    p = 2.81022636e-08f;
    p = fmaf(p, w, 3.43273939e-07f);
    p = fmaf(p, w, -3.5233877e-06f);
    p = fmaf(p, w, -4.39150654e-06f);
    p = fmaf(p, w, 0.00021858087f);
    p = fmaf(p, w, -0.00125372503f);
    p = fmaf(p, w, -0.00417768164f);
    p = fmaf(p, w, 0.246640727f);
    p = fmaf(p, w, 1.50140941f);
  } else {
    w = sqrtf(w) - 3.0f;
    p = -0.000200214257f;
    p = fmaf(p, w, 0.000100950558f);
    p = fmaf(p, w, 0.00134934322f);
    p = fmaf(p, w, -0.00367342844f);
    p = fmaf(p, w, 0.00573950773f);
    p = fmaf(p, w, -0.0076224613f);
    p = fmaf(p, w, 0.00943887047f);
    p = fmaf(p, w, 1.00167406f);
    p = fmaf(p, w, 2.83297682f);
  }
  return p * x;
}

// jax.random.normal element n (flat row-major index), key=(0, seed)
__device__ __forceinline__ float jax_normal_elem(uint32_t key, uint32_t n) {
  uint32_t o0, o1;
  threefry2x32(0u, key, 0u, n, o0, o1);
  uint32_t bits = o0 ^ o1;                     // partitionable 32-bit output
  float f = __uint_as_float((bits >> 9) | 0x3f800000u) - 1.0f;  // [0,1)
  const float lo = -0.99999994f;               // nextafter(-1,0)
  float u = fmaxf(lo, fmaf(f, 2.0f, lo));      // (maxval-minval) rounds to 2.0f
  return 1.41421356f * erfinv_xla(u);          // sqrt(2) in f32
}

// ---------------- mean over T, 2-stage (256 blocks stream, tiny reduce) ----------------
__global__ __launch_bounds__(256) void mean1_k(const float* __restrict__ A,
    const float* __restrict__ Vv, float* __restrict__ part) {
  const float* X = blockIdx.z ? Vv : A;
  const int b = blockIdx.x, pp = blockIdx.y, d = threadIdx.x;
  const float* p = X + ((size_t)b*T_ + (size_t)pp*256)*D_ + d;
  float s = 0.f;
  #pragma unroll 4
  for (int t = 0; t < 256; ++t) s += p[(size_t)t * D_];
  part[(((size_t)blockIdx.z*16 + b)*8 + pp)*256 + d] = s;
}

__global__ __launch_bounds__(256) void mean2_k(const float* __restrict__ part,
    float* __restrict__ muA, float* __restrict__ muV) {
  const int b = blockIdx.x;
  float* mu = blockIdx.y ? muV : muA;
  const float* pb = part + (((size_t)blockIdx.y*16 + b)*8)*256 + threadIdx.x;
  float s = 0.f;
  #pragma unroll
  for (int i = 0; i < 8; ++i) s += pb[i*256];
  mu[b*D_ + threadIdx.x] = s * (1.0f/(float)T_);
}

// ---------------- transpose A,V (f32 [b][t][d]) -> bf16 [b][d][T] ----------------
__global__ __launch_bounds__(256) void trans_k(const float* __restrict__ A,
    const float* __restrict__ V, __bf16* __restrict__ At, __bf16* __restrict__ Vt) {
  const float* X = blockIdx.z ? V : A;
  __bf16* Xt = blockIdx.z ? Vt : At;
  int b = blockIdx.y, t0 = blockIdx.x * 64, tid = threadIdx.x;
  __shared__ __bf16 TT[64 * 264];
  #pragma unroll
  for (int it = 0; it < 16; ++it) {
    int flat = it*1024 + tid*4;
    int t = flat >> 8, c = flat & 255;
    float4 f = *(const float4*)(X + ((size_t)b*T_ + t0 + t)*D_ + c);
    bf16x4 u;
    u[0] = (__bf16)f.x; u[1] = (__bf16)f.y; u[2] = (__bf16)f.z; u[3] = (__bf16)f.w;
    *(bf16x4*)&TT[t*264 + c] = u;
  }
  __syncthreads();
  int d = tid;
  __bf16* orow = Xt + ((size_t)b*D_ + d)*T_ + t0;
  #pragma unroll
  for (int g = 0; g < 8; ++g) {
    bf16x8 o;
    #pragma unroll
    for (int j = 0; j < 8; ++j) o[j] = TT[(g*8 + j)*264 + d];
    *(bf16x8*)(orow + g*8) = o;
  }
}

// ---------------- Sigma via MFMA: Sg = (Xt Xt^T - T mu mu^T)/(T-1) + jitter ----------------
__global__ __launch_bounds__(256) void sigma_mfma(const __bf16* __restrict__ At,
    const __bf16* __restrict__ Vt, const float* __restrict__ muA,
    const float* __restrict__ muV, float* __restrict__ SA, float* __restrict__ SV) {
  const __bf16* Xt = blockIdx.z ? Vt : At;
  const float* mu  = blockIdx.z ? muV : muA;
  float* Sg        = blockIdx.z ? SV  : SA;
  const int b  = blockIdx.y;
  const int i0 = (blockIdx.x >> 1) * 128;
  const int j0 = (blockIdx.x & 1) * 128;
  __shared__ __align__(16) char smem[32768];
  char* PA = smem;            // A panel [128 rows][8 chunks of 16B]
  char* PB = smem + 16384;    // B panel

  const int tid = threadIdx.x;
  const int wv = tid >> 6, lane = tid & 63;
  const int q15 = lane & 15, g = lane >> 4;
  const int wr = (wv >> 1) * 64, wc = (wv & 1) * 64;

  f32x4 acc[4][4];
  #pragma unroll
  for (int s = 0; s < 4; ++s)
    #pragma unroll
    for (int n = 0; n < 4; ++n) acc[s][n] = (f32x4){0.f,0.f,0.f,0.f};

  for (int t0 = 0; t0 < T_; t0 += 64) {
    __syncthreads();
    #pragma unroll
    for (int q = 0; q < 4; ++q) {
      int id = q*256 + tid;
      int row = id >> 3, c = id & 7;
      bf16x8 va = *(const bf16x8*)(Xt + ((size_t)b*D_ + i0 + row)*T_ + t0 + c*8);
      *(bf16x8*)(PA + row*128 + ((c ^ (row & 7)) << 4)) = va;
      bf16x8 vb = *(const bf16x8*)(Xt + ((size_t)b*D_ + j0 + row)*T_ + t0 + c*8);
      *(bf16x8*)(PB + row*128 + ((c ^ (row & 7)) << 4)) = vb;
    }
    __syncthreads();
    #pragma unroll
    for (int j = 0; j < 2; ++j) {
      bf16x8 af[4], bfr[4];
      #pragma unroll
      for (int s = 0; s < 4; ++s) {
        int ra = wr + 16*s + q15;
        af[s] = *(const bf16x8*)(PA + ra*128 + (((4*j + g) ^ (ra & 7)) << 4));
        int rb = wc + 16*s + q15;
        bfr[s] = *(const bf16x8*)(PB + rb*128 + (((4*j + g) ^ (rb & 7)) << 4));
      }
      #pragma unroll
      for (int s = 0; s < 4; ++s)
        #pragma unroll
        for (int n = 0; n < 4; ++n)
          acc[s][n] = __builtin_amdgcn_mfma_f32_16x16x32_bf16(af[s], bfr[n], acc[s][n], 0, 0, 0);
    }
  }
  const float invm = 1.0f / (float)(T_ - 1);
  #pragma unroll
  for (int s = 0; s < 4; ++s) {
    #pragma unroll
    for (int r = 0; r < 4; ++r) {
      int i = i0 + wr + 16*s + 4*g + r;
      float mi = mu[b*D_ + i] * (float)T_;
      #pragma unroll
      for (int n = 0; n < 4; ++n) {
        int j = j0 + wc + 16*n + q15;
        float v = (acc[s][n][r] - mi * mu[b*D_ + j]) * invm;
        if (i == j) v += 1e-6f;
        Sg[(size_t)b*D_*D_ + (size_t)i*D_ + j] = v;
      }
    }
  }
}

// ---------------- blocked Cholesky v5: LDS-resident L, 512 threads ----------------
// 8 waves/block: Schur GEMM rows split 2x finer (acc[4][4]) -> half the per-thread
// serial chain + 2 waves/SIMD latency hiding. Diag/TRSM phases unchanged.
#define CNB 32
#define LROW 36

__device__ __forceinline__ int offT(int q) { return 576*q*(15-q); }  // panel float offset

__global__ __launch_bounds__(512) void chol_k(float* __restrict__ SA, float* __restrict__ SV) {
  float* M = (blockIdx.y ? SV : SA) + (size_t)blockIdx.x * D_ * D_;
  __shared__ float Lp[32256];     // TRSM panels (129024 B)
  __shared__ float DG[32][36];    // current diag block
  __shared__ float PLT[32][36];   // transposed strictly-lower rows of diag factor
  __shared__ float PDinv[32];

  const int tid = threadIdx.x;
  const int hb  = tid >> 8;       // row-parity: this thread owns rows J+tr+32*(2k+hb)
  const int t8  = tid & 255;
  const int tr  = t8 >> 3;
  const int tc  = t8 & 7;

  for (int p = 0; p < 8; ++p) {
    const int J = p * 32;
    const int nr = 8 - p;
    __syncthreads();
    {
      const int nq = (D_ - J) * 8;
      for (int fl = tid; fl < nq; fl += 512) {
        int rr = fl >> 3, q4 = (fl & 7) * 4;
        float4 f = *(const float4*)(M + (size_t)(J + rr) * D_ + J + q4);
        float* dst = (rr < 32) ? &DG[rr][q4] : &Lp[offT(p) + (rr - 32)*LROW + q4];
        *(float4*)dst = f;
      }
    }
    float acc[4][4];
    #pragma unroll
    for (int k = 0; k < 4; ++k)
      #pragma unroll
      for (int o = 0; o < 4; ++o) acc[k][o] = 0.f;
    for (int q = 0; q < p; ++q) {
      const float* Pq = Lp + offT(q);
      const int ab = (J + tr - 32*q - 32) * LROW;
      const int bb = (J + tc - 32*q - 32) * LROW;
      #pragma unroll
      for (int jq = 0; jq < 8; ++jq) {
        float4 b0 = *(const float4*)(Pq + bb            + jq*4);
        float4 b1 = *(const float4*)(Pq + bb +  8*LROW  + jq*4);
        float4 b2 = *(const float4*)(Pq + bb + 16*LROW  + jq*4);
        float4 b3 = *(const float4*)(Pq + bb + 24*LROW  + jq*4);
        #pragma unroll
        for (int k = 0; k < 4; ++k) {
          const int krow = 2*k + hb;
          if (krow < nr) {
            float4 a = *(const float4*)(Pq + ab + krow*32*LROW + jq*4);
            acc[k][0] = fmaf(a.x,b0.x,acc[k][0]); acc[k][0] = fmaf(a.y,b0.y,acc[k][0]);
            acc[k][0] = fmaf(a.z,b0.z,acc[k][0]); acc[k][0] = fmaf(a.w,b0.w,acc[k][0]);
            acc[k][1] = fmaf(a.x,b1.x,acc[k][1]); acc[k][1] = fmaf(a.y,b1.y,acc[k][1]);
            acc[k][1] = fmaf(a.z,b1.z,acc[k][1]); acc[k][1] = fmaf(a.w,b1.w,acc[k][1]);
            acc[k][2] = fmaf(a.x,b2.x,acc[k][2]); acc[k][2] = fmaf(a.y,b2.y,acc[k][2]);
            acc[k][2] = fmaf(a.z,b2.z,acc[k][2]); acc[k][2] = fmaf(a.w,b2.w,acc[k][2]);
            acc[k][3] = fmaf(a.x,b3.x,acc[k][3]); acc[k][3] = fmaf(a.y,b3.y,acc[k][3]);
            acc[k][3] = fmaf(a.z,b3.z,acc[k][3]); acc[k][3] = fmaf(a.w,b3.w,acc[k][3]);
          }
        }
      }
    }
    __syncthreads();
    if (p > 0) {
      #pragma unroll
      for (int k = 0; k < 4; ++k) {
        const int krow = 2*k + hb;
        if (krow < nr) {
          float* dst = (krow == 0) ? &DG[tr][0] : &Lp[offT(p) + ((krow-1)*32 + tr)*LROW];
          #pragma unroll
          for (int o = 0; o < 4; ++o) dst[tc + 8*o] -= acc[k][o];
        }
      }
    }
    __syncthreads();
    if (tid < 32) {
      const int r = tid;
      float a[CNB];
      #pragma unroll
      for (int q4 = 0; q4 < CNB; q4 += 4) {
        float4 f = *(const float4*)&DG[r][q4];
        a[q4]=f.x; a[q4+1]=f.y; a[q4+2]=f.z; a[q4+3]=f.w;
      }
      #pragma unroll
      for (int j = 0; j < CNB; ++j) {
        float ajj = __shfl(a[j], j);
        float d = sqrtf(ajj);
        float dinv = 1.0f / d;
        float lcol = (r == j) ? d : a[j] * dinv;
        a[j] = lcol;
        if (r == j) PDinv[j] = dinv;
        PLT[j][r] = (r > j) ? lcol : 0.f;
        #pragma unroll
        for (int k = j + 1; k < CNB; ++k) {
          float lkj = __shfl(lcol, k);
          a[k] = fmaf(-lcol, lkj, a[k]);
        }
      }
      float* grow = M + (size_t)(J + r) * D_ + J;
      #pragma unroll
      for (int q4 = 0; q4 < CNB; q4 += 4) {
        float4 o;
        o.x = (q4   <= r) ? a[q4]   : 0.f;
        o.y = (q4+1 <= r) ? a[q4+1] : 0.f;
        o.z = (q4+2 <= r) ? a[q4+2] : 0.f;
        o.w = (q4+3 <= r) ? a[q4+3] : 0.f;
        *(float4*)(grow + q4) = o;
      }
    }
    __syncthreads();
    const int nb = D_ - J - CNB;
    if (tid < nb) {
      const int gi = J + CNB + tid;
      float* lr = &Lp[offT(p) + tid*LROW];
      float rr[CNB];
      #pragma unroll
      for (int q4 = 0; q4 < CNB; q4 += 4) {
        float4 f = *(const float4*)(lr + q4);
        rr[q4]=f.x; rr[q4+1]=f.y; rr[q4+2]=f.z; rr[q4+3]=f.w;
      }
      #pragma unroll
      for (int j = 0; j < CNB; ++j) {
        float xj = rr[j] * PDinv[j];
        rr[j] = xj;
        #pragma unroll
        for (int q = 0; q < 8; ++q) {
          if (q >= (j >> 2)) {
            float4 pv = *(const float4*)&PLT[j][q*4];
            rr[q*4+0] = fmaf(-xj, pv.x, rr[q*4+0]);
            rr[q*4+1] = fmaf(-xj, pv.y, rr[q*4+1]);
            rr[q*4+2] = fmaf(-xj, pv.z, rr[q*4+2]);
            rr[q*4+3] = fmaf(-xj, pv.w, rr[q*4+3]);
          }
        }
      }
      float* grow = M + (size_t)gi * D_ + J;
      #pragma unroll
      for (int q4 = 0; q4 < CNB; q4 += 4) {
        float4 o = make_float4(rr[q4], rr[q4+1], rr[q4+2], rr[q4+3]);
        *(float4*)(lr + q4)   = o;
        *(float4*)(grow + q4) = o;
      }
    }
  }
  __syncthreads();
  if (tid < 256) {
    float* rowt = M + (size_t)tid * D_;
    int k = tid + 1;
    while (k < D_ && (k & 3)) rowt[k++] = 0.f;
    const float4 z4 = make_float4(0.f, 0.f, 0.f, 0.f);
    for (; k < D_; k += 4) *(float4*)(rowt + k) = z4;
  }
}

// ---------------- K16 via MFMA: K = bf16(mu + eps @ L^T) ----------------
__global__ __launch_bounds__(256) void kgen_mfma(const float* __restrict__ L,
    const float* __restrict__ mu, __bf16* __restrict__ Kout, uint32_t key) {
  __shared__ __align__(16) char smem[40960];
  char* ES = smem;            // eps [64 t][8 chunks of 16B], chunk c at c^(t&7)
  char* LS = smem + 8192;     // L   [256 e][8 chunks of 16B], chunk c at c^(e&7)
  const int b   = blockIdx.y;
  const int t0  = blockIdx.x * 64;
  const int tid = threadIdx.x;
  const int wv = tid >> 6, lane = tid & 63;
  const int q15 = lane & 15, g = lane >> 4;
  const int e0 = wv * 64;
  const int tg = tid & 63;
  const int dgrp = tid >> 6;

  f32x4 acc[4][4];
  #pragma unroll
  for (int s = 0; s < 4; ++s)
    #pragma unroll
    for (int n = 0; n < 4; ++n) acc[s][n] = (f32x4){0.f,0.f,0.f,0.f};

  for (int d0 = 0; d0 < D_; d0 += 64) {
    __syncthreads();
    {
      uint32_t nbase = ((uint32_t)(b*T_ + t0 + tg))*256u + (uint32_t)(d0 + dgrp*16);
      #pragma unroll
      for (int h = 0; h < 2; ++h) {
        bf16x8 pk;
        #pragma unroll
        for (int i = 0; i < 8; ++i)
          pk[i] = (__bf16)jax_normal_elem(key, nbase + h*8 + i);
        int c = 2*dgrp + h;
        *(bf16x8*)(ES + tg*128 + ((c ^ (tg & 7)) << 4)) = pk;
      }
    }
    #pragma unroll
    for (int q = 0; q < 8; ++q) {
      int id = q*256 + tid;
      int row = id >> 3, c = id & 7;
      const float* lp = L + (size_t)b*D_*D_ + (size_t)row*D_ + d0 + c*8;
      float4 f0 = *(const float4*)lp;
      float4 f1 = *(const float4*)(lp + 4);
      bf16x8 pk;
      pk[0]=(__bf16)f0.x; pk[1]=(__bf16)f0.y; pk[2]=(__bf16)f0.z; pk[3]=(__bf16)f0.w;
      pk[4]=(__bf16)f1.x; pk[5]=(__bf16)f1.y; pk[6]=(__bf16)f1.z; pk[7]=(__bf16)f1.w;
      *(bf16x8*)(LS + row*128 + ((c ^ (row & 7)) << 4)) = pk;
    }
    __syncthreads();
    #pragma unroll
    for (int j = 0; j < 2; ++j) {
      bf16x8 af[4], bfr[4];
      #pragma unroll
      for (int s = 0; s < 4; ++s) {
        int ra = 16*s + q15;
        af[s] = *(const bf16x8*)(ES + ra*128 + (((4*j + g) ^ (ra & 7)) << 4));
        int rb = e0 + 16*s + q15;
        bfr[s] = *(const bf16x8*)(LS + rb*128 + (((4*j + g) ^ (rb & 7)) << 4));
      }
      #pragma unroll
      for (int s = 0; s < 4; ++s)
        #pragma unroll
        for (int n = 0; n < 4; ++n)
          acc[s][n] = __builtin_amdgcn_mfma_f32_16x16x32_bf16(af[s], bfr[n], acc[s][n], 0, 0, 0);
    }
  }
  #pragma unroll
  for (int n = 0; n < 4; ++n) {
    float me = mu[b*D_ + e0 + 16*n + q15];
    #pragma unroll
    for (int s = 0; s < 4; ++s)
      #pragma unroll
      for (int r = 0; r < 4; ++r)
        Kout[((size_t)b*T_ + t0 + 16*s + 4*g + r)*D_ + e0 + 16*n + q15] =
            (__bf16)(acc[s][n][r] + me);
  }
}

// ---------------- MFMA flash attention v3: 32 q-rows/wave, dbuf + async staging ----------------
// Each K/V-frag ds_read feeds 2 MFMAs (two Q-sets) -> per-CU LDS traffic halved vs v2.
// 256 blocks (1/CU), 4 waves, double-buffered 64KB tiles, T14 issue-early/write-late,
// ONE barrier per k-tile.
#define SCALE_ 0.0625f

__global__ __launch_bounds__(256, 1) void attn_mfma(const float* __restrict__ Qg,
    const __bf16* __restrict__ K16, const __bf16* __restrict__ Vt,
    __bf16* __restrict__ Og) {
  __shared__ __align__(16) char smem[131072];   // 2 x (KS 32KB + VS 32KB)

  const int tid  = threadIdx.x;
  const int wv   = tid >> 6;
  const int lane = tid & 63;
  const int q15  = lane & 15;
  const int g    = lane >> 4;
  const int sel  = lane >> 5;
  const int l7   = lane & 7;
  const int flat = blockIdx.x;
  const int b    = ((flat & 7) << 1) | ((flat >> 3) & 1);   // XCD-locality swizzle
  const int t0   = (flat >> 4) * 128;
  const int srcA = q15 | ((lane & 16) << 1);
  const int srcB = srcA + 16;

  // two Q fragment sets (scale folded): set u covers q-rows t0+wv*32+u*16+q15
  bf16x8 qf[2][8];
  #pragma unroll
  for (int u = 0; u < 2; ++u) {
    const float* qp = Qg + ((size_t)b*T_ + t0 + wv*32 + u*16 + q15)*D_ + 8*g;
    #pragma unroll
    for (int j = 0; j < 8; ++j) {
      float4 f0 = *(const float4*)(qp + 32*j);
      float4 f1 = *(const float4*)(qp + 32*j + 4);
      bf16x8 q;
      q[0] = (__bf16)(f0.x*SCALE_); q[1] = (__bf16)(f0.y*SCALE_);
      q[2] = (__bf16)(f0.z*SCALE_); q[3] = (__bf16)(f0.w*SCALE_);
      q[4] = (__bf16)(f1.x*SCALE_); q[5] = (__bf16)(f1.y*SCALE_);
      q[6] = (__bf16)(f1.z*SCALE_); q[7] = (__bf16)(f1.w*SCALE_);
      qf[u][j] = q;
    }
  }

  f32x4 oacc[2][16];
  #pragma unroll
  for (int u = 0; u < 2; ++u)
    #pragma unroll
    for (int n = 0; n < 16; ++n) oacc[u][n] = (f32x4){0.f, 0.f, 0.f, 0.f};
  float m[2] = {-INFINITY, -INFINITY}, lsum[2] = {0.f, 0.f};

  // per-thread staging indices (fixed across tiles)
  // prologue: stage tile 0 into buffer 0
  #pragma unroll
  for (int it = 0; it < 8; ++it) {
    int id = it*256 + tid;
    int k = id >> 5, c = id & 31;
    *(bf16x8*)(smem + k*512 + ((c ^ (k & 7)) << 4)) =
        *(const bf16x8*)(K16 + ((size_t)b*T_ + k)*D_ + c*8);
    int d = id >> 3, c2 = id & 7;
    *(bf16x8*)(smem + 32768 + d*128 + ((c2 ^ (d & 7)) << 4)) =
        *(const bf16x8*)(Vt + ((size_t)b*D_ + d)*T_ + c2*8);
  }
  __syncthreads();

  int cur = 0;
  for (int itn = 0; itn < T_/64; ++itn) {
    const char* KSb = smem + cur*65536;
    const char* VSb = KSb + 32768;
    char* KSn = smem + (cur^1)*65536;
    char* VSn = KSn + 32768;
    const int s0n = (itn + 1) * 64;
    const bool more = (itn + 1) < T_/64;

    // ---- T14 issue-early: next tile -> regs ----
    bf16x8 kst[8], vst[8];
    if (more) {
      #pragma unroll
      for (int it = 0; it < 8; ++it) {
        int id = it*256 + tid;
        int k = id >> 5, c = id & 31;
        kst[it] = *(const bf16x8*)(K16 + ((size_t)b*T_ + s0n + k)*D_ + c*8);
        int d = id >> 3, c2 = id & 7;
        vst[it] = *(const bf16x8*)(Vt + ((size_t)b*D_ + d)*T_ + s0n + c2*8);
      }
    }

    // ---- QK^T (swapped): each kf feeds both Q-sets ----
    f32x4 sacc[2][4];
    #pragma unroll
    for (int s = 0; s < 4; ++s) {
      f32x4 a0 = (f32x4){0.f,0.f,0.f,0.f};
      f32x4 a1 = (f32x4){0.f,0.f,0.f,0.f};
      const char* rowp = KSb + (16*s + q15)*512;
      #pragma unroll
      for (int j = 0; j < 8; ++j) {
        bf16x8 kf = *(const bf16x8*)(rowp + (((4*j + g) ^ l7) << 4));
        a0 = __builtin_amdgcn_mfma_f32_16x16x32_bf16(kf, qf[0][j], a0, 0, 0, 0);
        a1 = __builtin_amdgcn_mfma_f32_16x16x32_bf16(kf, qf[1][j], a1, 0, 0, 0);
      }
      sacc[0][s] = a0; sacc[1][s] = a1;
    }

    // ---- in-register online softmax, both sets ----
    float p[2][4][4];
    #pragma unroll
    for (int u = 0; u < 2; ++u) {
      float pmax = -INFINITY;
      #pragma unroll
      for (int s = 0; s < 4; ++s)
        #pragma unroll
        for (int r = 0; r < 4; ++r) { p[u][s][r] = sacc[u][s][r]; pmax = fmaxf(pmax, p[u][s][r]); }
      pmax = fmaxf(pmax, __shfl_xor(pmax, 16));
      pmax = fmaxf(pmax, __shfl_xor(pmax, 32));
      const bool keep = __all(pmax - m[u] <= 8.0f) != 0;   // defer-max (T13)
      float mnew = keep ? m[u] : fmaxf(m[u], pmax);
      float alpha = keep ? 1.0f : expf(m[u] - mnew);
      float ls = 0.f;
      #pragma unroll
      for (int s = 0; s < 4; ++s)
        #pragma unroll
        for (int r = 0; r < 4; ++r) { float e = expf(p[u][s][r] - mnew); p[u][s][r] = e; ls += e; }
      ls += __shfl_xor(ls, 16);
      ls += __shfl_xor(ls, 32);
      lsum[u] = lsum[u] * alpha + ls;
      m[u] = mnew;
      if (!keep) {
        #pragma unroll
        for (int r = 0; r < 4; ++r) {
          float ar = __shfl(alpha, 4*g + r);
          #pragma unroll
          for (int n = 0; n < 16; ++n) oacc[u][n][r] *= ar;
        }
      }
    }

    // ---- pack P -> bf16, redistribute to PV A-fragment lanes ----
    uint32_t pl0[2][4][2], pl1[2][4][2];
    #pragma unroll
    for (int u = 0; u < 2; ++u)
      #pragma unroll
      for (int s = 0; s < 4; ++s) {
        union { bf16x2 h; uint32_t w; } c0, c1;
        c0.h[0] = (__bf16)p[u][s][0]; c0.h[1] = (__bf16)p[u][s][1];
        c1.h[0] = (__bf16)p[u][s][2]; c1.h[1] = (__bf16)p[u][s][3];
        pl0[u][s][0] = (uint32_t)__shfl((int)c0.w, srcA);
        pl0[u][s][1] = (uint32_t)__shfl((int)c1.w, srcA);
        pl1[u][s][0] = (uint32_t)__shfl((int)c0.w, srcB);
        pl1[u][s][1] = (uint32_t)__shfl((int)c1.w, srcB);
      }

    // ---- PV: each vf feeds both Q-sets ----
    #pragma unroll
    for (int t = 0; t < 2; ++t) {
      union { uint32_t u4[4]; bf16x8 v; } pa[2];
      #pragma unroll
      for (int u = 0; u < 2; ++u) {
        pa[u].u4[0] = sel ? pl0[u][2*t+1][0] : pl0[u][2*t][0];
        pa[u].u4[1] = sel ? pl0[u][2*t+1][1] : pl0[u][2*t][1];
        pa[u].u4[2] = sel ? pl1[u][2*t+1][0] : pl1[u][2*t][0];
        pa[u].u4[3] = sel ? pl1[u][2*t+1][1] : pl1[u][2*t][1];
      }
      #pragma unroll
      for (int n = 0; n < 16; ++n) {
        bf16x8 vf = *(const bf16x8*)(VSb + (16*n + q15)*128 + (((4*t + g) ^ l7) << 4));
        oacc[0][n] = __builtin_amdgcn_mfma_f32_16x16x32_bf16(pa[0].v, vf, oacc[0][n], 0, 0, 0);
        oacc[1][n] = __builtin_amdgcn_mfma_f32_16x16x32_bf16(pa[1].v, vf, oacc[1][n], 0, 0, 0);
      }
    }

    // ---- T14 write-late: next tile regs -> other buffer ----
    if (more) {
      #pragma unroll
      for (int it = 0; it < 8; ++it) {
        int id = it*256 + tid;
        int k = id >> 5, c = id & 31;
        *(bf16x8*)(KSn + k*512 + ((c ^ (k & 7)) << 4)) = kst[it];
        int d = id >> 3, c2 = id & 7;
        *(bf16x8*)(VSn + d*128 + ((c2 ^ (d & 7)) << 4)) = vst[it];
      }
    }
    __syncthreads();
    cur ^= 1;
  }

  // ---- epilogue ----
  #pragma unroll
  for (int u = 0; u < 2; ++u)
    #pragma unroll
    for (int r = 0; r < 4; ++r) {
      float lr = __shfl(lsum[u], 4*g + r);
      float inv = 1.0f / lr;
      int row = t0 + wv*32 + u*16 + 4*g + r;
      __bf16* orow = Og + ((size_t)b*T_ + row)*D_ + q15;
      #pragma unroll
      for (int n = 0; n < 16; ++n)
        orow[16*n] = (__bf16)(oacc[u][n][r] * inv);
    }
}

// ---------------- gates + cosine combine (att inputs bf16) ----------------
__global__ __launch_bounds__(256) void comb_k(const float* __restrict__ A,
    const float* __restrict__ Vv, const __bf16* __restrict__ att1,
    const __bf16* __restrict__ att2, const float* __restrict__ WA,
    const float* __restrict__ WV, const float* __restrict__ bA,
    const float* __restrict__ bV, float* __restrict__ out) {
  int wv = threadIdx.x >> 6;
  int lane = threadIdx.x & 63;
  size_t row = (size_t)blockIdx.x * 4 + wv;
  size_t base = row * D_;
  int d = lane * 4;
  float4 a  = *(const float4*)(A + base + d);
  float4 v  = *(const float4*)(Vv + base + d);
  bf16x4 xb = *(const bf16x4*)(att1 + base + d);
  bf16x4 yb = *(const bf16x4*)(att2 + base + d);
  float4 x = make_float4((float)xb[0], (float)xb[1], (float)xb[2], (float)xb[3]);
  float4 y = make_float4((float)yb[0], (float)yb[1], (float)yb[2], (float)yb[3]);
  float4 w1 = *(const float4*)(WA + d);
  float4 w2 = *(const float4*)(WA + 256 + d);
  float4 w3 = *(const float4*)(WV + d);
  float4 w4 = *(const float4*)(WV + 256 + d);
  float sga = a.x*w1.x + a.y*w1.y + a.z*w1.z + a.w*w1.w
            + x.x*w2.x + x.y*w2.y + x.z*w2.z + x.w*w2.w;
  float sgv = v.x*w3.x + v.y*w3.y + v.z*w3.z + v.w*w3.w
            + y.x*w4.x + y.y*w4.y + y.z*w4.z + y.w*w4.w;
  float sav = a.x*v.x + a.y*v.y + a.z*v.z + a.w*v.w;
  float saa = a.x*a.x + a.y*a.y + a.z*a.z + a.w*a.w;
  float svv = v.x*v.x + v.y*v.y + v.z*v.z + v.w*v.w;
  #pragma unroll
  for (int mq = 32; mq; mq >>= 1) {
    sga += __shfl_xor(sga, mq);
    sgv += __shfl_xor(sgv, mq);
    sav += __shfl_xor(sav, mq);
    saa += __shfl_xor(saa, mq);
    svv += __shfl_xor(svv, mq);
  }
  float gA = 1.0f / (1.0f + expf(-(sga + bA[0])));
  float gV = 1.0f / (1.0f + expf(-(sgv + bV[0])));
  float cs = sav / fmaxf(sqrtf(saa) * sqrtf(svv), 1e-8f);
  float al = 1.0f / (1.0f + expf(-cs));
  float be = 1.0f - al;
  float4 o;
  o.x = al * (gA*a.x + (1.0f-gA)*x.x) + be * (gV*v.x + (1.0f-gV)*y.x);
  o.y = al * (gA*a.y + (1.0f-gA)*x.y) + be * (gV*v.y + (1.0f-gV)*y.y);
  o.z = al * (gA*a.z + (1.0f-gA)*x.z) + be * (gV*v.z + (1.0f-gV)*y.z);
  o.w = al * (gA*a.w + (1.0f-gA)*x.w) + be * (gV*v.w + (1.0f-gV)*y.w);
  *(float4*)(out + base + d) = o;
}

extern "C" void kernel_launch(void* const* d_in, const int* in_sizes, int n_in,
                              void* d_out, int out_size, void* d_ws, size_t ws_size,
                              hipStream_t stream) {
  (void)in_sizes; (void)n_in; (void)out_size; (void)ws_size;
  const float* A  = (const float*)d_in[0];
  const float* V  = (const float*)d_in[1];
  const float* WA = (const float*)d_in[2];
  const float* WV = (const float*)d_in[3];
  const float* bA = (const float*)d_in[4];
  const float* bV = (const float*)d_in[5];
  float* ws  = (float*)d_ws;
  float*  muA  = ws;                                   // 4096 f
  float*  muV  = muA + 4096;                           // 4096 f
  float*  LA   = muV + 4096;                           // 1,048,576 f
  float*  LV   = LA + (size_t)B_*D_*D_;                // 1,048,576 f
  __bf16* K16  = (__bf16*)(LV + (size_t)B_*D_*D_);     // N_ bf16 (N_/2 f-slots)
  __bf16* At16 = (__bf16*)((float*)K16 + N_/2);        // N_ bf16
  __bf16* Vt16 = (__bf16*)((float*)At16 + N_/2);       // N_ bf16
  __bf16* at1  = (__bf16*)((float*)Vt16 + N_/2);       // N_ bf16
  __bf16* at2  = (__bf16*)((float*)at1 + N_/2);        // N_ bf16
  float*  mws  = (float*)at1;   // mean partials scratch (65536 f), dead before attn writes at1

  mean1_k<<<dim3(16,8,2), dim3(256), 0, stream>>>(A, V, mws);
  mean2_k<<<dim3(16,2), dim3(256), 0, stream>>>(mws, muA, muV);
  trans_k<<<dim3(32,16,2), dim3(256), 0, stream>>>(A, V, At16, Vt16);
  sigma_mfma<<<dim3(4,16,2), dim3(256), 0, stream>>>(At16, Vt16, muA, muV, LA, LV);
  chol_k<<<dim3(16,2), dim3(512), 0, stream>>>(LA, LV);
  // K_v = resample(V, key 42): audio queries attend to it, values = V
  kgen_mfma<<<dim3(32,16), dim3(256), 0, stream>>>(LV, muV, K16, 42u);
  attn_mfma<<<dim3(256), dim3(256), 0, stream>>>(A, K16, Vt16, at1);
  // K_a = resample(A, key 43): visual queries attend to it, values = A
  kgen_mfma<<<dim3(32,16), dim3(256), 0, stream>>>(LA, muA, K16, 43u);
  attn_mfma<<<dim3(256), dim3(256), 0, stream>>>(V, K16, At16, at2);
  comb_k<<<dim3(8192), dim3(256), 0, stream>>>(A, V, at1, at2, WA, WV, bA, bV, (float*)d_out);
}

// Round 6
// 715.325 us; speedup vs baseline: 1.1810x; 1.1810x over previous
//
#include <hip/hip_runtime.h>
#include <stdint.h>
#include <math.h>

#define B_ 16
#define T_ 2048
#define D_ 256
#define N_ (B_*T_*D_)   // 8388608

typedef __attribute__((ext_vector_type(8)))  __bf16 bf16x8;
typedef __attribute__((ext_vector_type(4)))  __bf16 bf16x4;
typedef __attribute__((ext_vector_type(2)))  __bf16 bf16x2;
typedef __attribute__((ext_vector_type(4)))  float  f32x4;

// ---------------- JAX threefry2x32 (partitionable layout) ----------------
__device__ __forceinline__ uint32_t rotl32(uint32_t v, int r) {
  return (v << r) | (v >> (32 - r));
}

__device__ __forceinline__ void threefry2x32(uint32_t k0, uint32_t k1,
                                             uint32_t x0, uint32_t x1,
                                             uint32_t& o0, uint32_t& o1) {
  uint32_t ks2 = k0 ^ k1 ^ 0x1BD11BDAu;
#define TF_ROUND(r) { x0 += x1; x1 = rotl32(x1, r); x1 ^= x0; }
  x0 += k0; x1 += k1;
  TF_ROUND(13) TF_ROUND(15) TF_ROUND(26) TF_ROUND(6)
  x0 += k1; x1 += ks2 + 1u;
  TF_ROUND(17) TF_ROUND(29) TF_ROUND(16) TF_ROUND(24)
  x0 += ks2; x1 += k0 + 2u;
  TF_ROUND(13) TF_ROUND(15) TF_ROUND(26) TF_ROUND(6)
  x0 += k0; x1 += k1 + 3u;
  TF_ROUND(17) TF_ROUND(29) TF_ROUND(16) TF_ROUND(24)
  x0 += k1; x1 += ks2 + 4u;
  TF_ROUND(13) TF_ROUND(15) TF_ROUND(26) TF_ROUND(6)
  x0 += ks2; x1 += k0 + 5u;
#undef TF_ROUND
  o0 = x0; o1 = x1;
}

// XLA ErfInv f32 polynomial (Giles)
__device__ __forceinline__ float erfinv_xla(float x) {
  float w = -log1pf(-x * x);
  float p;
  if (w < 5.0f) {
    w -= 2.5f;
    p = 2.81022636e-08f;
    p = fmaf(p, w, 3.43273939e-07f);
    p = fmaf(p, w, -3.5233877e-06f);
    p = fmaf(p, w, -4.39150654e-06f);
    p = fmaf(p, w, 0.00021858087f);
    p = fmaf(p, w, -0.00125372503f);
    p = fmaf(p, w, -0.00417768164f);
    p = fmaf(p, w, 0.246640727f);
    p = fmaf(p, w, 1.50140941f);
  } else {
    w = sqrtf(w) - 3.0f;
    p = -0.000200214257f;
    p = fmaf(p, w, 0.000100950558f);
    p = fmaf(p, w, 0.00134934322f);
    p = fmaf(p, w, -0.00367342844f);
    p = fmaf(p, w, 0.00573950773f);
    p = fmaf(p, w, -0.0076224613f);
    p = fmaf(p, w, 0.00943887047f);
    p = fmaf(p, w, 1.00167406f);
    p = fmaf(p, w, 2.83297682f);
  }
  return p * x;
}

// jax.random.normal element n (flat row-major index), key=(0, seed)
__device__ __forceinline__ float jax_normal_elem(uint32_t key, uint32_t n) {
  uint32_t o0, o1;
  threefry2x32(0u, key, 0u, n, o0, o1);
  uint32_t bits = o0 ^ o1;                     // partitionable 32-bit output
  float f = __uint_as_float((bits >> 9) | 0x3f800000u) - 1.0f;  // [0,1)
  const float lo = -0.99999994f;               // nextafter(-1,0)
  float u = fmaxf(lo, fmaf(f, 2.0f, lo));      // (maxval-minval) rounds to 2.0f
  return 1.41421356f * erfinv_xla(u);          // sqrt(2) in f32
}

// ---------------- transpose A,V -> bf16 [b][d][T]  +  fused f32 mean partials ----------------
// Per-thread f32 partial col-sums over its 16 staged rows (same precision as old mean1),
// 4-way LDS reduce, one partial row per (mod,b,t-block) -> mean2 reduces 32.
__global__ __launch_bounds__(256) void trans_k(const float* __restrict__ A,
    const float* __restrict__ V, __bf16* __restrict__ At, __bf16* __restrict__ Vt,
    float* __restrict__ part) {
  const float* X = blockIdx.z ? V : A;
  __bf16* Xt = blockIdx.z ? Vt : At;
  int b = blockIdx.y, t0 = blockIdx.x * 64, tid = threadIdx.x;
  __shared__ __bf16 TT[64 * 264];
  __shared__ float PS[4][256];
  float ps0 = 0.f, ps1 = 0.f, ps2 = 0.f, ps3 = 0.f;
  #pragma unroll
  for (int it = 0; it < 16; ++it) {
    int flat = it*1024 + tid*4;
    int t = flat >> 8, c = flat & 255;
    float4 f = *(const float4*)(X + ((size_t)b*T_ + t0 + t)*D_ + c);
    ps0 += f.x; ps1 += f.y; ps2 += f.z; ps3 += f.w;
    bf16x4 u;
    u[0] = (__bf16)f.x; u[1] = (__bf16)f.y; u[2] = (__bf16)f.z; u[3] = (__bf16)f.w;
    *(bf16x4*)&TT[t*264 + c] = u;
  }
  *(float4*)&PS[tid >> 6][(tid & 63) * 4] = make_float4(ps0, ps1, ps2, ps3);
  __syncthreads();
  // mean partial for col tid over this 64-row t-block
  part[(((size_t)blockIdx.z*16 + b)*32 + blockIdx.x)*256 + tid] =
      PS[0][tid] + PS[1][tid] + PS[2][tid] + PS[3][tid];
  int d = tid;
  __bf16* orow = Xt + ((size_t)b*D_ + d)*T_ + t0;
  #pragma unroll
  for (int g = 0; g < 8; ++g) {
    bf16x8 o;
    #pragma unroll
    for (int j = 0; j < 8; ++j) o[j] = TT[(g*8 + j)*264 + d];
    *(bf16x8*)(orow + g*8) = o;
  }
}

__global__ __launch_bounds__(256) void mean2_k(const float* __restrict__ part,
    float* __restrict__ muA, float* __restrict__ muV) {
  const int b = blockIdx.x;
  float* mu = blockIdx.y ? muV : muA;
  const float* pb = part + (((size_t)blockIdx.y*16 + b)*32)*256 + threadIdx.x;
  float s = 0.f;
  #pragma unroll
  for (int i = 0; i < 32; ++i) s += pb[i*256];
  mu[b*D_ + threadIdx.x] = s * (1.0f/(float)T_);
}

// ---------------- Sigma via MFMA: Sg = (Xt Xt^T - T mu mu^T)/(T-1) + jitter ----------------
__global__ __launch_bounds__(256) void sigma_mfma(const __bf16* __restrict__ At,
    const __bf16* __restrict__ Vt, const float* __restrict__ muA,
    const float* __restrict__ muV, float* __restrict__ SA, float* __restrict__ SV) {
  const __bf16* Xt = blockIdx.z ? Vt : At;
  const float* mu  = blockIdx.z ? muV : muA;
  float* Sg        = blockIdx.z ? SV  : SA;
  const int b  = blockIdx.y;
  const int i0 = (blockIdx.x >> 1) * 128;
  const int j0 = (blockIdx.x & 1) * 128;
  __shared__ __align__(16) char smem[32768];
  char* PA = smem;            // A panel [128 rows][8 chunks of 16B]
  char* PB = smem + 16384;    // B panel

  const int tid = threadIdx.x;
  const int wv = tid >> 6, lane = tid & 63;
  const int q15 = lane & 15, g = lane >> 4;
  const int wr = (wv >> 1) * 64, wc = (wv & 1) * 64;

  f32x4 acc[4][4];
  #pragma unroll
  for (int s = 0; s < 4; ++s)
    #pragma unroll
    for (int n = 0; n < 4; ++n) acc[s][n] = (f32x4){0.f,0.f,0.f,0.f};

  for (int t0 = 0; t0 < T_; t0 += 64) {
    __syncthreads();
    #pragma unroll
    for (int q = 0; q < 4; ++q) {
      int id = q*256 + tid;
      int row = id >> 3, c = id & 7;
      bf16x8 va = *(const bf16x8*)(Xt + ((size_t)b*D_ + i0 + row)*T_ + t0 + c*8);
      *(bf16x8*)(PA + row*128 + ((c ^ (row & 7)) << 4)) = va;
      bf16x8 vb = *(const bf16x8*)(Xt + ((size_t)b*D_ + j0 + row)*T_ + t0 + c*8);
      *(bf16x8*)(PB + row*128 + ((c ^ (row & 7)) << 4)) = vb;
    }
    __syncthreads();
    #pragma unroll
    for (int j = 0; j < 2; ++j) {
      bf16x8 af[4], bfr[4];
      #pragma unroll
      for (int s = 0; s < 4; ++s) {
        int ra = wr + 16*s + q15;
        af[s] = *(const bf16x8*)(PA + ra*128 + (((4*j + g) ^ (ra & 7)) << 4));
        int rb = wc + 16*s + q15;
        bfr[s] = *(const bf16x8*)(PB + rb*128 + (((4*j + g) ^ (rb & 7)) << 4));
      }
      #pragma unroll
      for (int s = 0; s < 4; ++s)
        #pragma unroll
        for (int n = 0; n < 4; ++n)
          acc[s][n] = __builtin_amdgcn_mfma_f32_16x16x32_bf16(af[s], bfr[n], acc[s][n], 0, 0, 0);
    }
  }
  const float invm = 1.0f / (float)(T_ - 1);
  #pragma unroll
  for (int s = 0; s < 4; ++s) {
    #pragma unroll
    for (int r = 0; r < 4; ++r) {
      int i = i0 + wr + 16*s + 4*g + r;
      float mi = mu[b*D_ + i] * (float)T_;
      #pragma unroll
      for (int n = 0; n < 4; ++n) {
        int j = j0 + wc + 16*n + q15;
        float v = (acc[s][n][r] - mi * mu[b*D_ + j]) * invm;
        if (i == j) v += 1e-6f;
        Sg[(size_t)b*D_*D_ + (size_t)i*D_ + j] = v;
      }
    }
  }
}

// ---------------- blocked Cholesky v4: fully LDS-resident L (256 thr, known 197us) ----------------
#define CNB 32
#define LROW 36

__device__ __forceinline__ int offT(int q) { return 576*q*(15-q); }  // panel float offset

__global__ __launch_bounds__(256) void chol_k(float* __restrict__ SA, float* __restrict__ SV) {
  float* M = (blockIdx.y ? SV : SA) + (size_t)blockIdx.x * D_ * D_;
  __shared__ float Lp[32256];     // TRSM panels (129024 B)
  __shared__ float DG[32][36];    // current diag block
  __shared__ float PLT[32][36];   // transposed strictly-lower rows of diag factor
  __shared__ float PDinv[32];

  const int tid = threadIdx.x;
  const int tr  = tid >> 3;
  const int tc  = tid & 7;

  for (int p = 0; p < 8; ++p) {
    const int J = p * 32;
    const int nr = 8 - p;
    __syncthreads();
    {
      const int nq = (D_ - J) * 8;
      for (int fl = tid; fl < nq; fl += 256) {
        int rr = fl >> 3, q4 = (fl & 7) * 4;
        float4 f = *(const float4*)(M + (size_t)(J + rr) * D_ + J + q4);
        float* dst = (rr < 32) ? &DG[rr][q4] : &Lp[offT(p) + (rr - 32)*LROW + q4];
        *(float4*)dst = f;
      }
    }
    float acc[8][4];
    #pragma unroll
    for (int k = 0; k < 8; ++k)
      #pragma unroll
      for (int o = 0; o < 4; ++o) acc[k][o] = 0.f;
    for (int q = 0; q < p; ++q) {
      const float* Pq = Lp + offT(q);
      const int ab = (J + tr - 32*q - 32) * LROW;
      const int bb = (J + tc - 32*q - 32) * LROW;
      #pragma unroll
      for (int jq = 0; jq < 8; ++jq) {
        float4 b0 = *(const float4*)(Pq + bb            + jq*4);
        float4 b1 = *(const float4*)(Pq + bb +  8*LROW  + jq*4);
        float4 b2 = *(const float4*)(Pq + bb + 16*LROW  + jq*4);
        float4 b3 = *(const float4*)(Pq + bb + 24*LROW  + jq*4);
        #pragma unroll
        for (int k = 0; k < 8; ++k) {
          if (k < nr) {
            float4 a = *(const float4*)(Pq + ab + k*32*LROW + jq*4);
            acc[k][0] = fmaf(a.x,b0.x,acc[k][0]); acc[k][0] = fmaf(a.y,b0.y,acc[k][0]);
            acc[k][0] = fmaf(a.z,b0.z,acc[k][0]); acc[k][0] = fmaf(a.w,b0.w,acc[k][0]);
            acc[k][1] = fmaf(a.x,b1.x,acc[k][1]); acc[k][1] = fmaf(a.y,b1.y,acc[k][1]);
            acc[k][1] = fmaf(a.z,b1.z,acc[k][1]); acc[k][1] = fmaf(a.w,b1.w,acc[k][1]);
            acc[k][2] = fmaf(a.x,b2.x,acc[k][2]); acc[k][2] = fmaf(a.y,b2.y,acc[k][2]);
            acc[k][2] = fmaf(a.z,b2.z,acc[k][2]); acc[k][2] = fmaf(a.w,b2.w,acc[k][2]);
            acc[k][3] = fmaf(a.x,b3.x,acc[k][3]); acc[k][3] = fmaf(a.y,b3.y,acc[k][3]);
            acc[k][3] = fmaf(a.z,b3.z,acc[k][3]); acc[k][3] = fmaf(a.w,b3.w,acc[k][3]);
          }
        }
      }
    }
    __syncthreads();
    if (p > 0) {
      #pragma unroll
      for (int k = 0; k < 8; ++k) {
        if (k < nr) {
          float* dst = (k == 0) ? &DG[tr][0] : &Lp[offT(p) + ((k-1)*32 + tr)*LROW];
          #pragma unroll
          for (int o = 0; o < 4; ++o) dst[tc + 8*o] -= acc[k][o];
        }
      }
    }
    __syncthreads();
    if (tid < 32) {
      const int r = tid;
      float a[CNB];
      #pragma unroll
      for (int q4 = 0; q4 < CNB; q4 += 4) {
        float4 f = *(const float4*)&DG[r][q4];
        a[q4]=f.x; a[q4+1]=f.y; a[q4+2]=f.z; a[q4+3]=f.w;
      }
      #pragma unroll
      for (int j = 0; j < CNB; ++j) {
        float ajj = __shfl(a[j], j);
        float d = sqrtf(ajj);
        float dinv = 1.0f / d;
        float lcol = (r == j) ? d : a[j] * dinv;
        a[j] = lcol;
        if (r == j) PDinv[j] = dinv;
        PLT[j][r] = (r > j) ? lcol : 0.f;
        #pragma unroll
        for (int k = j + 1; k < CNB; ++k) {
          float lkj = __shfl(lcol, k);
          a[k] = fmaf(-lcol, lkj, a[k]);
        }
      }
      float* grow = M + (size_t)(J + r) * D_ + J;
      #pragma unroll
      for (int q4 = 0; q4 < CNB; q4 += 4) {
        float4 o;
        o.x = (q4   <= r) ? a[q4]   : 0.f;
        o.y = (q4+1 <= r) ? a[q4+1] : 0.f;
        o.z = (q4+2 <= r) ? a[q4+2] : 0.f;
        o.w = (q4+3 <= r) ? a[q4+3] : 0.f;
        *(float4*)(grow + q4) = o;
      }
    }
    __syncthreads();
    const int nb = D_ - J - CNB;
    if (tid < nb) {
      const int gi = J + CNB + tid;
      float* lr = &Lp[offT(p) + tid*LROW];
      float rr[CNB];
      #pragma unroll
      for (int q4 = 0; q4 < CNB; q4 += 4) {
        float4 f = *(const float4*)(lr + q4);
        rr[q4]=f.x; rr[q4+1]=f.y; rr[q4+2]=f.z; rr[q4+3]=f.w;
      }
      #pragma unroll
      for (int j = 0; j < CNB; ++j) {
        float xj = rr[j] * PDinv[j];
        rr[j] = xj;
        #pragma unroll
        for (int q = 0; q < 8; ++q) {
          if (q >= (j >> 2)) {
            float4 pv = *(const float4*)&PLT[j][q*4];
            rr[q*4+0] = fmaf(-xj, pv.x, rr[q*4+0]);
            rr[q*4+1] = fmaf(-xj, pv.y, rr[q*4+1]);
            rr[q*4+2] = fmaf(-xj, pv.z, rr[q*4+2]);
            rr[q*4+3] = fmaf(-xj, pv.w, rr[q*4+3]);
          }
        }
      }
      float* grow = M + (size_t)gi * D_ + J;
      #pragma unroll
      for (int q4 = 0; q4 < CNB; q4 += 4) {
        float4 o = make_float4(rr[q4], rr[q4+1], rr[q4+2], rr[q4+3]);
        *(float4*)(lr + q4)   = o;
        *(float4*)(grow + q4) = o;
      }
    }
  }
  __syncthreads();
  {
    float* rowt = M + (size_t)tid * D_;
    int k = tid + 1;
    while (k < D_ && (k & 3)) rowt[k++] = 0.f;
    const float4 z4 = make_float4(0.f, 0.f, 0.f, 0.f);
    for (; k < D_; k += 4) *(float4*)(rowt + k) = z4;
  }
}

// ---------------- K16 via MFMA: K = bf16(mu + eps @ L^T) ----------------
__global__ __launch_bounds__(256) void kgen_mfma(const float* __restrict__ L,
    const float* __restrict__ mu, __bf16* __restrict__ Kout, uint32_t key) {
  __shared__ __align__(16) char smem[40960];
  char* ES = smem;            // eps [64 t][8 chunks of 16B], chunk c at c^(t&7)
  char* LS = smem + 8192;     // L   [256 e][8 chunks of 16B], chunk c at c^(e&7)
  const int b   = blockIdx.y;
  const int t0  = blockIdx.x * 64;
  const int tid = threadIdx.x;
  const int wv = tid >> 6, lane = tid & 63;
  const int q15 = lane & 15, g = lane >> 4;
  const int e0 = wv * 64;
  const int tg = tid & 63;
  const int dgrp = tid >> 6;

  f32x4 acc[4][4];
  #pragma unroll
  for (int s = 0; s < 4; ++s)
    #pragma unroll
    for (int n = 0; n < 4; ++n) acc[s][n] = (f32x4){0.f,0.f,0.f,0.f};

  for (int d0 = 0; d0 < D_; d0 += 64) {
    __syncthreads();
    {
      uint32_t nbase = ((uint32_t)(b*T_ + t0 + tg))*256u + (uint32_t)(d0 + dgrp*16);
      #pragma unroll
      for (int h = 0; h < 2; ++h) {
        bf16x8 pk;
        #pragma unroll
        for (int i = 0; i < 8; ++i)
          pk[i] = (__bf16)jax_normal_elem(key, nbase + h*8 + i);
        int c = 2*dgrp + h;
        *(bf16x8*)(ES + tg*128 + ((c ^ (tg & 7)) << 4)) = pk;
      }
    }
    #pragma unroll
    for (int q = 0; q < 8; ++q) {
      int id = q*256 + tid;
      int row = id >> 3, c = id & 7;
      const float* lp = L + (size_t)b*D_*D_ + (size_t)row*D_ + d0 + c*8;
      float4 f0 = *(const float4*)lp;
      float4 f1 = *(const float4*)(lp + 4);
      bf16x8 pk;
      pk[0]=(__bf16)f0.x; pk[1]=(__bf16)f0.y; pk[2]=(__bf16)f0.z; pk[3]=(__bf16)f0.w;
      pk[4]=(__bf16)f1.x; pk[5]=(__bf16)f1.y; pk[6]=(__bf16)f1.z; pk[7]=(__bf16)f1.w;
      *(bf16x8*)(LS + row*128 + ((c ^ (row & 7)) << 4)) = pk;
    }
    __syncthreads();
    #pragma unroll
    for (int j = 0; j < 2; ++j) {
      bf16x8 af[4], bfr[4];
      #pragma unroll
      for (int s = 0; s < 4; ++s) {
        int ra = 16*s + q15;
        af[s] = *(const bf16x8*)(ES + ra*128 + (((4*j + g) ^ (ra & 7)) << 4));
        int rb = e0 + 16*s + q15;
        bfr[s] = *(const bf16x8*)(LS + rb*128 + (((4*j + g) ^ (rb & 7)) << 4));
      }
      #pragma unroll
      for (int s = 0; s < 4; ++s)
        #pragma unroll
        for (int n = 0; n < 4; ++n)
          acc[s][n] = __builtin_amdgcn_mfma_f32_16x16x32_bf16(af[s], bfr[n], acc[s][n], 0, 0, 0);
    }
  }
  #pragma unroll
  for (int n = 0; n < 4; ++n) {
    float me = mu[b*D_ + e0 + 16*n + q15];
    #pragma unroll
    for (int s = 0; s < 4; ++s)
      #pragma unroll
      for (int r = 0; r < 4; ++r)
        Kout[((size_t)b*T_ + t0 + 16*s + 4*g + r)*D_ + e0 + 16*n + q15] =
            (__bf16)(acc[s][n][r] + me);
  }
}

// ---------------- MFMA flash attention v2 (known-good): swapped-QK^T ----------------
#define SCALE_ 0.0625f

__global__ __launch_bounds__(256, 2) void attn_mfma(const float* __restrict__ Qg,
    const __bf16* __restrict__ K16, const __bf16* __restrict__ Vt,
    __bf16* __restrict__ Og) {
  __shared__ __align__(16) char smem[65536];
  char* KSb = smem;              // [64 k][32 chunks of 16B], chunk c stored at c^(k&7)
  char* VSb = smem + 32768;      // [256 d][8 chunks of 16B], chunk c stored at c^(d&7)

  const int tid  = threadIdx.x;
  const int wv   = tid >> 6;
  const int lane = tid & 63;
  const int q15  = lane & 15;
  const int g    = lane >> 4;
  const int sel  = lane >> 5;
  const int l7   = lane & 7;
  const int flat = blockIdx.x;
  const int b    = ((flat & 7) << 1) | ((flat >> 3) & 1);
  const int t0   = (flat >> 4) * 64;
  const int qrow = t0 + wv*16 + q15;
  const int srcA = q15 | ((lane & 16) << 1);
  const int srcB = srcA + 16;

  bf16x8 qf[8];
  {
    const float* qp = Qg + ((size_t)b*T_ + qrow)*D_ + 8*g;
    #pragma unroll
    for (int j = 0; j < 8; ++j) {
      float4 f0 = *(const float4*)(qp + 32*j);
      float4 f1 = *(const float4*)(qp + 32*j + 4);
      bf16x8 q;
      q[0] = (__bf16)(f0.x*SCALE_); q[1] = (__bf16)(f0.y*SCALE_);
      q[2] = (__bf16)(f0.z*SCALE_); q[3] = (__bf16)(f0.w*SCALE_);
      q[4] = (__bf16)(f1.x*SCALE_); q[5] = (__bf16)(f1.y*SCALE_);
      q[6] = (__bf16)(f1.z*SCALE_); q[7] = (__bf16)(f1.w*SCALE_);
      qf[j] = q;
    }
  }

  f32x4 oacc[16];
  #pragma unroll
  for (int n = 0; n < 16; ++n) oacc[n] = (f32x4){0.f, 0.f, 0.f, 0.f};
  float m = -INFINITY, lsum = 0.f;

  for (int s0 = 0; s0 < T_; s0 += 64) {
    __syncthreads();
    #pragma unroll
    for (int it = 0; it < 8; ++it) {
      int id = it*256 + tid;
      int k = id >> 5, c = id & 31;
      *(bf16x8*)(KSb + k*512 + (((c ^ (k & 7))) << 4)) =
          *(const bf16x8*)(K16 + ((size_t)b*T_ + s0 + k)*D_ + c*8);
    }
    #pragma unroll
    for (int it = 0; it < 8; ++it) {
      int id = it*256 + tid;
      int d = id >> 3, c = id & 7;
      *(bf16x8*)(VSb + d*128 + ((c ^ (d & 7)) << 4)) =
          *(const bf16x8*)(Vt + ((size_t)b*D_ + d)*T_ + s0 + c*8);
    }
    __syncthreads();

    f32x4 sacc[4];
    #pragma unroll
    for (int s = 0; s < 4; ++s) {
      f32x4 acc = (f32x4){0.f, 0.f, 0.f, 0.f};
      const char* rowp = KSb + (16*s + q15)*512;
      #pragma unroll
      for (int j = 0; j < 8; ++j) {
        bf16x8 kf = *(const bf16x8*)(rowp + (((4*j + g) ^ l7) << 4));
        acc = __builtin_amdgcn_mfma_f32_16x16x32_bf16(kf, qf[j], acc, 0, 0, 0);
      }
      sacc[s] = acc;
    }

    float p[4][4];
    float pmax = -INFINITY;
    #pragma unroll
    for (int s = 0; s < 4; ++s)
      #pragma unroll
      for (int r = 0; r < 4; ++r) { p[s][r] = sacc[s][r]; pmax = fmaxf(pmax, p[s][r]); }
    pmax = fmaxf(pmax, __shfl_xor(pmax, 16));
    pmax = fmaxf(pmax, __shfl_xor(pmax, 32));
    const bool keep = __all(pmax - m <= 8.0f) != 0;
    float mnew = keep ? m : fmaxf(m, pmax);
    float alpha = keep ? 1.0f : expf(m - mnew);
    float ls = 0.f;
    #pragma unroll
    for (int s = 0; s < 4; ++s)
      #pragma unroll
      for (int r = 0; r < 4; ++r) { float e = expf(p[s][r] - mnew); p[s][r] = e; ls += e; }
    ls += __shfl_xor(ls, 16);
    ls += __shfl_xor(ls, 32);
    lsum = lsum * alpha + ls;
    m = mnew;
    if (!keep) {
      #pragma unroll
      for (int r = 0; r < 4; ++r) {
        float ar = __shfl(alpha, 4*g + r);
        #pragma unroll
        for (int n = 0; n < 16; ++n) oacc[n][r] *= ar;
      }
    }

    uint32_t w[4][2];
    #pragma unroll
    for (int s = 0; s < 4; ++s) {
      union { bf16x2 h; uint32_t u; } c0, c1;
      c0.h[0] = (__bf16)p[s][0]; c0.h[1] = (__bf16)p[s][1];
      c1.h[0] = (__bf16)p[s][2]; c1.h[1] = (__bf16)p[s][3];
      w[s][0] = c0.u; w[s][1] = c1.u;
    }
    uint32_t pl0[4][2], pl1[4][2];
    #pragma unroll
    for (int s = 0; s < 4; ++s)
      #pragma unroll
      for (int h = 0; h < 2; ++h) {
        pl0[s][h] = (uint32_t)__shfl((int)w[s][h], srcA);
        pl1[s][h] = (uint32_t)__shfl((int)w[s][h], srcB);
      }

    #pragma unroll
    for (int t = 0; t < 2; ++t) {
      union { uint32_t u[4]; bf16x8 v; } pa;
      pa.u[0] = sel ? pl0[2*t+1][0] : pl0[2*t][0];
      pa.u[1] = sel ? pl0[2*t+1][1] : pl0[2*t][1];
      pa.u[2] = sel ? pl1[2*t+1][0] : pl1[2*t][0];
      pa.u[3] = sel ? pl1[2*t+1][1] : pl1[2*t][1];
      #pragma unroll
      for (int n = 0; n < 16; ++n) {
        bf16x8 vf = *(const bf16x8*)(VSb + (16*n + q15)*128 + (((4*t + g) ^ l7) << 4));
        oacc[n] = __builtin_amdgcn_mfma_f32_16x16x32_bf16(pa.v, vf, oacc[n], 0, 0, 0);
      }
    }
  }

  #pragma unroll
  for (int r = 0; r < 4; ++r) {
    float lr = __shfl(lsum, 4*g + r);
    float inv = 1.0f / lr;
    int row = t0 + wv*16 + 4*g + r;
    __bf16* orow = Og + ((size_t)b*T_ + row)*D_ + q15;
    #pragma unroll
    for (int n = 0; n < 16; ++n)
      orow[16*n] = (__bf16)(oacc[n][r] * inv);
  }
}

// ---------------- gates + cosine combine (att inputs bf16) ----------------
__global__ __launch_bounds__(256) void comb_k(const float* __restrict__ A,
    const float* __restrict__ Vv, const __bf16* __restrict__ att1,
    const __bf16* __restrict__ att2, const float* __restrict__ WA,
    const float* __restrict__ WV, const float* __restrict__ bA,
    const float* __restrict__ bV, float* __restrict__ out) {
  int wv = threadIdx.x >> 6;
  int lane = threadIdx.x & 63;
  size_t row = (size_t)blockIdx.x * 4 + wv;
  size_t base = row * D_;
  int d = lane * 4;
  float4 a  = *(const float4*)(A + base + d);
  float4 v  = *(const float4*)(Vv + base + d);
  bf16x4 xb = *(const bf16x4*)(att1 + base + d);
  bf16x4 yb = *(const bf16x4*)(att2 + base + d);
  float4 x = make_float4((float)xb[0], (float)xb[1], (float)xb[2], (float)xb[3]);
  float4 y = make_float4((float)yb[0], (float)yb[1], (float)yb[2], (float)yb[3]);
  float4 w1 = *(const float4*)(WA + d);
  float4 w2 = *(const float4*)(WA + 256 + d);
  float4 w3 = *(const float4*)(WV + d);
  float4 w4 = *(const float4*)(WV + 256 + d);
  float sga = a.x*w1.x + a.y*w1.y + a.z*w1.z + a.w*w1.w
            + x.x*w2.x + x.y*w2.y + x.z*w2.z + x.w*w2.w;
  float sgv = v.x*w3.x + v.y*w3.y + v.z*w3.z + v.w*w3.w
            + y.x*w4.x + y.y*w4.y + y.z*w4.z + y.w*w4.w;
  float sav = a.x*v.x + a.y*v.y + a.z*v.z + a.w*v.w;
  float saa = a.x*a.x + a.y*a.y + a.z*a.z + a.w*a.w;
  float svv = v.x*v.x + v.y*v.y + v.z*v.z + v.w*v.w;
  #pragma unroll
  for (int mq = 32; mq; mq >>= 1) {
    sga += __shfl_xor(sga, mq);
    sgv += __shfl_xor(sgv, mq);
    sav += __shfl_xor(sav, mq);
    saa += __shfl_xor(saa, mq);
    svv += __shfl_xor(svv, mq);
  }
  float gA = 1.0f / (1.0f + expf(-(sga + bA[0])));
  float gV = 1.0f / (1.0f + expf(-(sgv + bV[0])));
  float cs = sav / fmaxf(sqrtf(saa) * sqrtf(svv), 1e-8f);
  float al = 1.0f / (1.0f + expf(-cs));
  float be = 1.0f - al;
  float4 o;
  o.x = al * (gA*a.x + (1.0f-gA)*x.x) + be * (gV*v.x + (1.0f-gV)*y.x);
  o.y = al * (gA*a.y + (1.0f-gA)*x.y) + be * (gV*v.y + (1.0f-gV)*y.y);
  o.z = al * (gA*a.z + (1.0f-gA)*x.z) + be * (gV*v.z + (1.0f-gV)*y.z);
  o.w = al * (gA*a.w + (1.0f-gA)*x.w) + be * (gV*v.w + (1.0f-gV)*y.w);
  *(float4*)(out + base + d) = o;
}

extern "C" void kernel_launch(void* const* d_in, const int* in_sizes, int n_in,
                              void* d_out, int out_size, void* d_ws, size_t ws_size,
                              hipStream_t stream) {
  (void)in_sizes; (void)n_in; (void)out_size; (void)ws_size;
  const float* A  = (const float*)d_in[0];
  const float* V  = (const float*)d_in[1];
  const float* WA = (const float*)d_in[2];
  const float* WV = (const float*)d_in[3];
  const float* bA = (const float*)d_in[4];
  const float* bV = (const float*)d_in[5];
  float* ws  = (float*)d_ws;
  float*  muA  = ws;                                   // 4096 f
  float*  muV  = muA + 4096;                           // 4096 f
  float*  LA   = muV + 4096;                           // 1,048,576 f
  float*  LV   = LA + (size_t)B_*D_*D_;                // 1,048,576 f
  __bf16* K16  = (__bf16*)(LV + (size_t)B_*D_*D_);     // N_ bf16 (N_/2 f-slots)
  __bf16* At16 = (__bf16*)((float*)K16 + N_/2);        // N_ bf16
  __bf16* Vt16 = (__bf16*)((float*)At16 + N_/2);       // N_ bf16
  __bf16* at1  = (__bf16*)((float*)Vt16 + N_/2);       // N_ bf16
  __bf16* at2  = (__bf16*)((float*)at1 + N_/2);        // N_ bf16
  float*  mws  = (float*)at1;   // mean partials scratch (262144 f), dead before attn writes at1

  // trans_k computes mean partials (fused mean1) + bf16 transposes
  trans_k<<<dim3(32,16,2), dim3(256), 0, stream>>>(A, V, At16, Vt16, mws);
  mean2_k<<<dim3(16,2), dim3(256), 0, stream>>>(mws, muA, muV);
  sigma_mfma<<<dim3(4,16,2), dim3(256), 0, stream>>>(At16, Vt16, muA, muV, LA, LV);
  chol_k<<<dim3(16,2), dim3(256), 0, stream>>>(LA, LV);
  // K_v = resample(V, key 42): audio queries attend to it, values = V
  kgen_mfma<<<dim3(32,16), dim3(256), 0, stream>>>(LV, muV, K16, 42u);
  attn_mfma<<<dim3(512), dim3(256), 0, stream>>>(A, K16, Vt16, at1);
  // K_a = resample(A, key 43): visual queries attend to it, values = A
  kgen_mfma<<<dim3(32,16), dim3(256), 0, stream>>>(LA, muA, K16, 43u);
  attn_mfma<<<dim3(512), dim3(256), 0, stream>>>(V, K16, At16, at2);
  comb_k<<<dim3(8192), dim3(256), 0, stream>>>(A, V, at1, at2, WA, WV, bA, bV, (float*)d_out);
}